// Round 1
// baseline (158.741 us; speedup 1.0000x reference)
//
#include <hip/hip_runtime.h>
#include <hip/hip_bf16.h>

typedef _Float16 f16;
typedef _Float16 f16x8 __attribute__((ext_vector_type(8)));
typedef float f32x4 __attribute__((ext_vector_type(4)));

#define NN 200000
#define KK 512
#define CC 64
#define JJ 32
// W_frag: 48 F-ksteps (16 w1 | 16 wh | 16 wl) x 4 coltiles x 64 lanes x 8 f16
#define WFRAG_ELEMS (48 * 4 * 64 * 8) /* 98304 f16 = 192 KiB */

// Pack W into MFMA-B fragment order: elem idx = ((kF*4 + ct)*64 + lane)*8 + i
// holds W[Fk = (kF&15)*32 + (lane>>4)*8 + i][c = ct*16 + (lane&15)], section kF>>4:
//   0: w1 = -0.5*(exp(-lv)-1)   (vs xx, centered variance term)
//   1: wh = f16(mu*exp(-lv))    (vs xh and xl)
//   2: wl = residual of wh      (vs xh)
__global__ __launch_bounds__(256) void fill_w(const float* __restrict__ mu,
                                              const float* __restrict__ lv,
                                              f16* __restrict__ wfrag) {
  int idx = blockIdx.x * 256 + threadIdx.x;
  int i = idx & 7, l = (idx >> 3) & 63, ct = (idx >> 9) & 3, kF = idx >> 11;
  int k = (kF & 15) * 32 + (l >> 4) * 8 + i;
  int c = ct * 16 + (l & 15);
  int sec = kF >> 4;
  float lvv = lv[c * KK + k];
  float w;
  if (sec == 0) {
    w = -0.5f * expm1f(-lvv);
  } else {
    float w2 = mu[c * KK + k] * expf(-lvv);
    float wh = (float)(f16)w2;
    w = (sec == 1) ? wh : (w2 - wh);
  }
  wfrag[idx] = (f16)w;
}

// bias[j][c] = log(alpha*beta[c] + njk[j][c]) - 0.5*(sum_k(mu^2*iv + lv) + K*ln(2pi))
__global__ __launch_bounds__(64) void fill_bias(const float* __restrict__ mu,
                                                const float* __restrict__ lv,
                                                const float* __restrict__ beta,
                                                const float* __restrict__ njk,
                                                const float* __restrict__ alphap,
                                                float* __restrict__ bias) {
  int c = blockIdx.x;
  int lane = threadIdx.x;
  float s = 0.0f;
  for (int k = lane; k < KK; k += 64) {
    float l2 = lv[c * KK + k];
    float m = mu[c * KK + k];
    s += fmaf(m * m, expf(-l2), l2);
  }
  #pragma unroll
  for (int d = 1; d < 64; d <<= 1) s += __shfl_xor(s, d, 64);
  float base = -0.5f * (s + 512.0f * 1.8378770664093453f);
  if (lane < JJ)
    bias[lane * CC + c] = logf(alphap[0] * beta[c] + njk[lane * CC + c]) + base;
}

// One wave (64 threads) per 32-row tile. 16x16x32 f16 MFMA, 2 row-tiles x 4 col-tiles.
// Layouts (m89-verified): A row=l&15, k=(l>>4)*8+i; D col=l&15, row=(l>>4)*4+reg.
__global__ __launch_bounds__(64, 3) void gmm_main(
    const float* __restrict__ x, const int* __restrict__ ms,
    const f16* __restrict__ wfrag, const float* __restrict__ bias,
    float* __restrict__ out) {
  const int lane = threadIdx.x;
  const int lr = lane & 15;   // A row / D col / B col within tile
  const int kg = lane >> 4;   // k-group (8 consecutive k each)
  const int row0 = blockIdx.x * 32;

  f32x4 acc[2][4];
  #pragma unroll
  for (int rt = 0; rt < 2; ++rt)
    #pragma unroll
    for (int ct = 0; ct < 4; ++ct) acc[rt][ct] = (f32x4)0.0f;

  const float* xp0 = x + (size_t)(row0 + lr) * KK + kg * 8;
  const float* xp1 = x + (size_t)(row0 + 16 + lr) * KK + kg * 8;
  const f16* wb = wfrag + lane * 8;

  #pragma unroll 2
  for (int s = 0; s < 16; ++s) {
    f16x8 fxx[2], fxh[2], fxl[2];
    #pragma unroll
    for (int rt = 0; rt < 2; ++rt) {
      const float* xp = rt ? xp1 : xp0;
      f32x4 a = *reinterpret_cast<const f32x4*>(xp + s * 32);
      f32x4 b = *reinterpret_cast<const f32x4*>(xp + s * 32 + 4);
      #pragma unroll
      for (int i = 0; i < 8; ++i) {
        float v = (i < 4) ? a[i] : b[i - 4];
        f16 h = (f16)v;
        fxh[rt][i] = h;
        fxl[rt][i] = (f16)(v - (float)h);
        fxx[rt][i] = (f16)(v * v);
      }
    }
    f16x8 bw1[4], bwh[4], bwl[4];
    #pragma unroll
    for (int ct = 0; ct < 4; ++ct) {
      bw1[ct] = *reinterpret_cast<const f16x8*>(wb + (size_t)(((0 + s) * 4 + ct) * 64) * 8);
      bwh[ct] = *reinterpret_cast<const f16x8*>(wb + (size_t)(((16 + s) * 4 + ct) * 64) * 8);
      bwl[ct] = *reinterpret_cast<const f16x8*>(wb + (size_t)(((32 + s) * 4 + ct) * 64) * 8);
    }
    #pragma unroll
    for (int ct = 0; ct < 4; ++ct)
      #pragma unroll
      for (int rt = 0; rt < 2; ++rt) {
        acc[rt][ct] = __builtin_amdgcn_mfma_f32_16x16x32_f16(fxx[rt], bw1[ct], acc[rt][ct], 0, 0, 0);
        acc[rt][ct] = __builtin_amdgcn_mfma_f32_16x16x32_f16(fxh[rt], bwh[ct], acc[rt][ct], 0, 0, 0);
        acc[rt][ct] = __builtin_amdgcn_mfma_f32_16x16x32_f16(fxh[rt], bwl[ct], acc[rt][ct], 0, 0, 0);
        acc[rt][ct] = __builtin_amdgcn_mfma_f32_16x16x32_f16(fxl[rt], bwh[ct], acc[rt][ct], 0, 0, 0);
      }
  }

  // Epilogue: bias add + softmax across 64 cols (4 regs x 16 lanes) + store.
  #pragma unroll
  for (int rt = 0; rt < 2; ++rt) {
    int rbase = row0 + rt * 16 + kg * 4;
    #pragma unroll
    for (int r = 0; r < 4; ++r) {
      int j = ms[rbase + r];
      const float* bj = bias + j * CC + lr;
      float v0 = acc[rt][0][r] + bj[0];
      float v1 = acc[rt][1][r] + bj[16];
      float v2 = acc[rt][2][r] + bj[32];
      float v3 = acc[rt][3][r] + bj[48];
      float m = fmaxf(fmaxf(v0, v1), fmaxf(v2, v3));
      #pragma unroll
      for (int d = 1; d < 16; d <<= 1) m = fmaxf(m, __shfl_xor(m, d, 64));
      float e0 = __expf(v0 - m), e1 = __expf(v1 - m);
      float e2 = __expf(v2 - m), e3 = __expf(v3 - m);
      float sum = (e0 + e1) + (e2 + e3);
      #pragma unroll
      for (int d = 1; d < 16; d <<= 1) sum += __shfl_xor(sum, d, 64);
      float inv = 1.0f / sum;
      float* o = out + (size_t)(rbase + r) * CC + lr;
      o[0]  = e0 * inv;
      o[16] = e1 * inv;
      o[32] = e2 * inv;
      o[48] = e3 * inv;
    }
  }
}

extern "C" void kernel_launch(void* const* d_in, const int* in_sizes, int n_in,
                              void* d_out, int out_size, void* d_ws, size_t ws_size,
                              hipStream_t stream) {
  const float* x     = (const float*)d_in[0];
  const float* mu    = (const float*)d_in[1];
  const float* lv    = (const float*)d_in[2];
  const float* beta  = (const float*)d_in[3];
  const float* njk   = (const float*)d_in[4];
  const float* alpha = (const float*)d_in[5];
  const int*   ms    = (const int*)d_in[6];
  float* out = (float*)d_out;

  f16* wfrag  = (f16*)d_ws;
  float* bias = (float*)((char*)d_ws + WFRAG_ELEMS * sizeof(f16));

  fill_w<<<WFRAG_ELEMS / 256, 256, 0, stream>>>(mu, lv, wfrag);
  fill_bias<<<CC, 64, 0, stream>>>(mu, lv, beta, njk, alpha, bias);
  gmm_main<<<NN / 32, 64, 0, stream>>>(x, ms, wfrag, bias, out);
}